// Round 3
// baseline (1335.465 us; speedup 1.0000x reference)
//
#include <hip/hip_runtime.h>
#include <hip/hip_bf16.h>
#include <math.h>

// Problem: input (16,1024,512) f32, codebook (8192,512) f32
#define N_ROWS 16384
#define DIM    512
#define VOCAB  8192

typedef __attribute__((ext_vector_type(8))) short short8;
typedef __attribute__((ext_vector_type(4))) float f32x4;

__device__ inline unsigned short f2bf(float f) {      // RNE f32 -> bf16 bits
    unsigned u = __float_as_uint(f);
    u += 0x7fff + ((u >> 16) & 1);
    return (unsigned short)(u >> 16);
}
__device__ inline float bf2f(unsigned short b) {
    return __uint_as_float(((unsigned)b) << 16);
}

__device__ inline void gload16(const void* g, void* l) {
    __builtin_amdgcn_global_load_lds(
        (const __attribute__((address_space(1))) void*)g,
        (__attribute__((address_space(3))) void*)l, 16, 0, 0);
}

// swizzled LDS fragment read: row rh (128B pitch), 16B slot, slot ^= rh&7
__device__ inline short8 frag(const char* base, int rh, int slot) {
    return *(const short8*)(base + rh * 128 + (((slot) ^ (rh & 7)) << 4));
}

__device__ inline void top2_ins(float s, int v, float& s1, int& i1, float& s2, int& i2) {
    if (s < s1 || (s == s1 && v < i1)) { s2 = s1; i2 = i1; s1 = s; i1 = v; }
    else if (s < s2 || (s == s2 && v < i2)) { s2 = s; i2 = v; }
}

// ---------------------------------------------------------------------------
// Split fp32 -> bf16 hi + bf16 lo
// ---------------------------------------------------------------------------
__global__ void k_split(const float* __restrict__ in, unsigned short* __restrict__ hi,
                        unsigned short* __restrict__ lo, int n4) {
    int t = blockIdx.x * 256 + threadIdx.x;
    if (t >= n4) return;
    float4 v = reinterpret_cast<const float4*>(in)[t];
    ushort4 h, l;
    h.x = f2bf(v.x); l.x = f2bf(v.x - bf2f(h.x));
    h.y = f2bf(v.y); l.y = f2bf(v.y - bf2f(h.y));
    h.z = f2bf(v.z); l.z = f2bf(v.z - bf2f(h.z));
    h.w = f2bf(v.w); l.w = f2bf(v.w - bf2f(h.w));
    reinterpret_cast<ushort4*>(hi)[t] = h;
    reinterpret_cast<ushort4*>(lo)[t] = l;
}

// hi-only split for the codebook (lo side of B is dropped: dot ~= x . Hi)
__global__ void k_split_hi(const float* __restrict__ in, unsigned short* __restrict__ hi,
                           int n4) {
    int t = blockIdx.x * 256 + threadIdx.x;
    if (t >= n4) return;
    float4 v = reinterpret_cast<const float4*>(in)[t];
    ushort4 h;
    h.x = f2bf(v.x); h.y = f2bf(v.y); h.z = f2bf(v.z); h.w = f2bf(v.w);
    reinterpret_cast<ushort4*>(hi)[t] = h;
}

// ---------------------------------------------------------------------------
// c2[v] = sum(codebook[v]^2) fp32
// ---------------------------------------------------------------------------
__global__ void k_c2(const float* __restrict__ cb, float* __restrict__ c2) {
    int row  = blockIdx.x * 4 + (threadIdx.x >> 6);
    int lane = threadIdx.x & 63;
    const float4* p = reinterpret_cast<const float4*>(cb + (size_t)row * DIM);
    float s = 0.f;
#pragma unroll
    for (int i = 0; i < 2; ++i) {
        float4 v = p[lane + i * 64];
        s += v.x * v.x + v.y * v.y + v.z * v.z + v.w * v.w;
    }
#pragma unroll
    for (int off = 32; off > 0; off >>= 1) s += __shfl_xor(s, off, 64);
    if (lane == 0) c2[row] = s;
}

// ---------------------------------------------------------------------------
// 8-phase 256x256 bf16 MFMA GEMM (virtual K = 1024: [xhi;xlo] x cbhi) with
// fused per-128-col top-2 argmin epilogue.
// 8 waves (2Mx4N, interleaved: row = mf*32+wm*16, col = nf*64+wn*16), BK=64,
// 128 KiB LDS (2 dbuf x (A,B) x 2 halves x [128][64] bf16, XOR slot swizzle).
// Counted vmcnt(4) at P4/P8 only; fragment reuse: 12/4/8/0 ds_reads per phase.
// ---------------------------------------------------------------------------
#define LDSA(b, h) (As + (b) * 32768 + (h) * 16384)
#define LDSB(b, h) (Bs + (b) * 32768 + (h) * 16384)

#define READ_A(BUF, H) do { const char* _b = LDSA(BUF, H);                  \
    _Pragma("unroll") for (int m = 0; m < 4; ++m)                           \
    _Pragma("unroll") for (int kk = 0; kk < 2; ++kk)                        \
        af[m][kk] = frag(_b, m * 32 + arow, kk * 4 + lg); } while (0)

#define READ_B0(BUF) do { const char* _b = LDSB(BUF, 0);                    \
    _Pragma("unroll") for (int n = 0; n < 2; ++n)                           \
    _Pragma("unroll") for (int kk = 0; kk < 2; ++kk)                        \
        bf0[n][kk] = frag(_b, n * 64 + brow, kk * 4 + lg); } while (0)

#define READ_B1(BUF) do { const char* _b = LDSB(BUF, 1);                    \
    _Pragma("unroll") for (int n = 0; n < 2; ++n)                           \
    _Pragma("unroll") for (int kk = 0; kk < 2; ++kk)                        \
        bf1[n][kk] = frag(_b, n * 64 + brow, kk * 4 + lg); } while (0)

#define STAGE_A2(BUF, H, T, SRC) do {                                       \
    const char* _s = (const char*)(SRC) +                                   \
        (rowBase + (H) * 128 + sgrow) * 1024 + (((T) & 7) << 7) + sgoff;    \
    char* _d = LDSA(BUF, H) + sgdst;                                        \
    gload16(_s, _d); gload16(_s + 65536, _d + 8192); } while (0)

#define STAGE_B2(BUF, H, T) do {                                            \
    const char* _s = (const char*)cbhi +                                    \
        (colBase + (H) * 128 + sgrow) * 1024 + (((T) & 7) << 7) + sgoff;    \
    char* _d = LDSB(BUF, H) + sgdst;                                        \
    gload16(_s, _d); gload16(_s + 65536, _d + 8192); } while (0)

#define SCHEDB __builtin_amdgcn_sched_barrier(0)
#define BARX   __builtin_amdgcn_s_barrier()
#define VMC4   asm volatile("s_waitcnt vmcnt(4)" ::: "memory")
#define VMC0   asm volatile("s_waitcnt vmcnt(0)" ::: "memory")

#define PHASE_TAIL(MB, BSET, NB) do {                                       \
    BARX;                                                                   \
    asm volatile("s_waitcnt lgkmcnt(0)" ::: "memory"); SCHEDB;              \
    __builtin_amdgcn_s_setprio(1);                                          \
    _Pragma("unroll") for (int kk = 0; kk < 2; ++kk)                        \
    _Pragma("unroll") for (int m = 0; m < 4; ++m)                           \
    _Pragma("unroll") for (int n = 0; n < 2; ++n)                           \
        acc[(MB) * 4 + m][(NB) * 2 + n] =                                   \
            __builtin_amdgcn_mfma_f32_16x16x32_bf16(                        \
                af[m][kk], BSET[n][kk], acc[(MB) * 4 + m][(NB) * 2 + n],    \
                0, 0, 0);                                                   \
    __builtin_amdgcn_s_setprio(0); SCHEDB;                                  \
    BARX; } while (0)

__launch_bounds__(512, 2)
__global__ void k_mfma8(const unsigned short* __restrict__ xhi,
                        const unsigned short* __restrict__ xlo,
                        const unsigned short* __restrict__ cbhi,
                        const float* __restrict__ c2,
                        float4* __restrict__ part) {
    __shared__ __align__(16) char Lds[131072];
    char* As = Lds;            // [buf][half][128 rows][64 bf16], slot^=(row&7)
    char* Bs = Lds + 65536;

    const int tid  = threadIdx.x;
    const int w8   = tid >> 6;
    const int wm   = w8 >> 2, wn = w8 & 3;
    const int lane = tid & 63, l15 = lane & 15, lg = lane >> 4;
    const int arow = wm * 16 + l15;
    const int brow = wn * 16 + l15;
    const int sgrow = 8 * w8 + (lane >> 3);
    const int sgoff = ((lane & 7) ^ (lane >> 3)) << 4;
    const int sgdst = w8 * 1024;

    // XCD-aware swizzle: grid 2048 = 64 row-tiles x 32 col-tiles
    const int g  = blockIdx.x;
    const int wg = (g & 7) * 256 + (g >> 3);
    const int by = wg >> 5, bx = wg & 31;
    const size_t rowBase = (size_t)by * 256;
    const size_t colBase = (size_t)bx * 256;

    f32x4 acc[8][4];
#pragma unroll
    for (int m = 0; m < 8; ++m)
#pragma unroll
        for (int n = 0; n < 4; ++n) acc[m][n] = (f32x4)0.f;
    short8 af[4][2], bf0[2][2], bf1[2][2];

    // Prologue: tile0 -> buf0 all 4 halves; tile1 -> buf1 {Ah0,Bh0}
    STAGE_A2(0, 0, 0, xhi); STAGE_B2(0, 0, 0);
    STAGE_A2(0, 1, 0, xhi); STAGE_B2(0, 1, 0);
    STAGE_A2(1, 0, 1, xhi); STAGE_B2(1, 0, 1);
    VMC4;
    BARX;

    for (int i = 0; i < 8; ++i) {               // 16 K-tiles, 2 per iter
        const bool more = (i < 7);
        const int t1 = 2 * i + 1, t2 = 2 * i + 2, t3 = 2 * i + 3;
        const unsigned short* A1 = (t1 < 8) ? xhi : xlo;
        const unsigned short* A2 = (t2 < 8) ? xhi : xlo;
        const unsigned short* A3 = (t3 < 8) ? xhi : xlo;
        // P1: quadrant (m0,n0) of buf0
        READ_A(0, 0); READ_B0(0);
        STAGE_A2(1, 1, t1, A1);
        PHASE_TAIL(0, bf0, 0);
        // P2: (m0,n1)
        READ_B1(0);
        STAGE_B2(1, 1, t1);
        PHASE_TAIL(0, bf1, 1);
        // P3: (m1,n1)
        READ_A(0, 1);
        if (more) STAGE_A2(0, 0, t2, A2);
        PHASE_TAIL(1, bf1, 1);
        // P4: (m1,n0) — reg-only MFMA; counted vmcnt
        if (more) { STAGE_B2(0, 0, t2); VMC4; } else { VMC0; }
        PHASE_TAIL(1, bf0, 0);
        // P5: (m0,n0) of buf1
        READ_A(1, 0); READ_B0(1);
        if (more) STAGE_A2(0, 1, t2, A2);
        PHASE_TAIL(0, bf0, 0);
        // P6: (m0,n1)
        READ_B1(1);
        if (more) STAGE_B2(0, 1, t2);
        PHASE_TAIL(0, bf1, 1);
        // P7: (m1,n1)
        READ_A(1, 1);
        if (more) STAGE_A2(1, 0, t3, A3);
        PHASE_TAIL(1, bf1, 1);
        // P8: (m1,n0)
        if (more) { STAGE_B2(1, 0, t3); VMC4; }
        PHASE_TAIL(1, bf0, 0);
    }

    // Epilogue: score = c2 - 2*acc; top-2 per row per 128-col half.
    // C frag: col = l15, row = 4*lg + reg. Per-wave rows mf*32+wm*16+4lg+reg.
    float c2v[4];
#pragma unroll
    for (int nf = 0; nf < 4; ++nf) c2v[nf] = c2[colBase + nf * 64 + wn * 16 + l15];

    float4* scr = (float4*)Lds;   // [256 rows][8 = wn*2+h], reuse of staging LDS
#pragma unroll
    for (int mf = 0; mf < 8; ++mf) {
#pragma unroll
        for (int r = 0; r < 4; ++r) {
#pragma unroll
            for (int h = 0; h < 2; ++h) {
                float s1 = INFINITY, s2 = INFINITY;
                int   i1 = 0x7fffffff, i2 = 0x7fffffff;
#pragma unroll
                for (int n = 0; n < 2; ++n) {
                    int nf = h * 2 + n;
                    float s = fmaf(-2.f, acc[mf][nf][r], c2v[nf]);
                    int  vv = (int)colBase + nf * 64 + wn * 16 + l15;
                    top2_ins(s, vv, s1, i1, s2, i2);
                }
#pragma unroll
                for (int off = 1; off < 16; off <<= 1) {
                    float t1 = __shfl_xor(s1, off, 64); int j1 = __shfl_xor(i1, off, 64);
                    float t2 = __shfl_xor(s2, off, 64); int j2 = __shfl_xor(i2, off, 64);
                    bool bfirst = (t1 < s1) || (t1 == s1 && j1 < i1);
                    if (bfirst) {
                        float ns; int ni;
                        if (s1 < t2 || (s1 == t2 && i1 < j2)) { ns = s1; ni = i1; }
                        else                                   { ns = t2; ni = j2; }
                        s1 = t1; i1 = j1; s2 = ns; i2 = ni;
                    } else if (t1 < s2 || (t1 == s2 && j1 < i2)) { s2 = t1; i2 = j1; }
                }
                if (l15 == 0)
                    scr[(mf * 32 + wm * 16 + 4 * lg + r) * 8 + wn * 2 + h] =
                        make_float4(s1, __int_as_float(i1), s2, __int_as_float(i2));
            }
        }
    }
    __syncthreads();
    {   // 512 threads: row = tid>>1, half = tid&1 -> merge 4 wn entries
        int row = tid >> 1, h = tid & 1;
        float s1 = INFINITY, s2 = INFINITY;
        int   i1 = 0x7fffffff, i2 = 0x7fffffff;
#pragma unroll
        for (int q = 0; q < 4; ++q) {
            float4 p = scr[row * 8 + q * 2 + h];
            top2_ins(p.x, __float_as_int(p.y), s1, i1, s2, i2);
            top2_ins(p.z, __float_as_int(p.w), s1, i1, s2, i2);
        }
        part[(rowBase + row) * 64 + bx * 2 + h] =
            make_float4(s1, __int_as_float(i1), s2, __int_as_float(i2));
    }
}

// ---------------------------------------------------------------------------
// Per-row final: approx global min over 64 per-128-col top2s; exact fp32
// rescore of all candidates within min+1.0 (>20 sigma of split error).
// ---------------------------------------------------------------------------
__global__ void k_select(const float4* __restrict__ part,
                         const float* __restrict__ x,
                         const float* __restrict__ cb,
                         const float* __restrict__ c2,
                         float* __restrict__ out_idx_f,
                         int* __restrict__ idx_i,
                         int* __restrict__ used) {
    int wv   = threadIdx.x >> 6;
    int lane = threadIdx.x & 63;
    int row  = blockIdx.x * 4 + wv;
    float4 p = part[(size_t)row * 64 + lane];
    float s1 = p.x; int i1 = __float_as_int(p.y);
    float s2 = p.z; int i2 = __float_as_int(p.w);
    float gm = s1;
#pragma unroll
    for (int off = 1; off < 64; off <<= 1) gm = fminf(gm, __shfl_xor(gm, off, 64));
    float thresh = gm + 1.0f;
    unsigned long long m1 = __ballot(s1 <= thresh);
    unsigned long long m2 = __ballot(s2 <= thresh);
    float be = INFINITY; int bi = 0x7fffffff;
    const float4* xr = reinterpret_cast<const float4*>(x + (size_t)row * DIM);
    while (m1 | m2) {
        int vi;
        if (m1) { int t = __ffsll(m1) - 1; m1 &= m1 - 1; vi = __shfl(i1, t); }
        else    { int t = __ffsll(m2) - 1; m2 &= m2 - 1; vi = __shfl(i2, t); }
        const float4* cr = reinterpret_cast<const float4*>(cb + (size_t)vi * DIM);
        float d = 0.f;
#pragma unroll
        for (int q = 0; q < 2; ++q) {
            float4 a = xr[q * 64 + lane];
            float4 b = cr[q * 64 + lane];
            d += a.x * b.x + a.y * b.y + a.z * b.z + a.w * b.w;
        }
#pragma unroll
        for (int off = 1; off < 64; off <<= 1) d += __shfl_xor(d, off, 64);
        float se = c2[vi] - 2.f * d;
        if (se < be || (se == be && vi < bi)) { be = se; bi = vi; }
    }
    if (lane == 0) {
        out_idx_f[row] = (float)bi;
        idx_i[row]     = bi;
        used[bi]       = 1;
    }
}

__global__ void k_streak(const int* __restrict__ streak_in,
                         const int* __restrict__ used,
                         float* __restrict__ out) {
    int v = blockIdx.x * 256 + threadIdx.x;
    if (v < VOCAB) out[v] = used[v] ? 0.f : (float)(streak_in[v] + 1);
}

__global__ void k_gather(const float* __restrict__ cb,
                         const int* __restrict__ idx_i,
                         float* __restrict__ out) {
    size_t t  = (size_t)blockIdx.x * 256 + threadIdx.x;
    int    n  = (int)(t >> 7);
    int    d4 = (int)(t & 127);
    reinterpret_cast<float4*>(out)[t] =
        reinterpret_cast<const float4*>(cb + (size_t)idx_i[n] * DIM)[d4];
}

extern "C" void kernel_launch(void* const* d_in, const int* in_sizes, int n_in,
                              void* d_out, int out_size, void* d_ws, size_t ws_size,
                              hipStream_t stream) {
    const float* x      = (const float*)d_in[0];
    const float* cb     = (const float*)d_in[1];
    const int*   streak = (const int*)d_in[2];

    float* out       = (float*)d_out;
    float* out_embed = out;
    float* out_idx   = out + (size_t)N_ROWS * DIM;
    float* out_strk  = out_idx + N_ROWS;

    char* ws = (char*)d_ws;
    unsigned short* xhi  = (unsigned short*)(ws);                 // 16 MB
    unsigned short* xlo  = (unsigned short*)(ws + (16u << 20));   // 16 MB
    unsigned short* cbhi = (unsigned short*)(ws + (32u << 20));   // 8 MB
    float* c2    = (float*)(ws + (48u << 20));                    // 32 KB
    int*   idx_i = (int*)(ws + (48u << 20) + (1u << 16));         // 64 KB
    int*   used  = (int*)(ws + (48u << 20) + (2u << 16));         // 32 KB
    float4* part = (float4*)(ws + (49u << 20));                   // 16 MB

    hipMemsetAsync(used, 0, VOCAB * sizeof(int), stream);
    k_split<<<(N_ROWS * DIM / 4) / 256, 256, 0, stream>>>(x, xhi, xlo, N_ROWS * DIM / 4);
    k_split_hi<<<(VOCAB * DIM / 4) / 256, 256, 0, stream>>>(cb, cbhi, VOCAB * DIM / 4);
    k_c2<<<VOCAB / 4, 256, 0, stream>>>(cb, c2);
    k_mfma8<<<2048, 512, 0, stream>>>(xhi, xlo, cbhi, c2, part);
    k_select<<<N_ROWS / 4, 256, 0, stream>>>(part, x, cb, c2, out_idx, idx_i, used);
    k_streak<<<VOCAB / 256, 256, 0, stream>>>(streak, used, out_strk);
    k_gather<<<(N_ROWS * DIM / 4) / 256, 256, 0, stream>>>(cb, idx_i, out_embed);
}

// Round 4
// 403.520 us; speedup vs baseline: 3.3095x; 3.3095x over previous
//
#include <hip/hip_runtime.h>
#include <hip/hip_bf16.h>
#include <math.h>

// Problem: input (16,1024,512) f32, codebook (8192,512) f32
#define N_ROWS 16384
#define DIM    512
#define VOCAB  8192

typedef __attribute__((ext_vector_type(8))) short short8;
typedef __attribute__((ext_vector_type(4))) float f32x4;

__device__ inline unsigned short f2bf(float f) {      // RNE f32 -> bf16 bits
    unsigned u = __float_as_uint(f);
    u += 0x7fff + ((u >> 16) & 1);
    return (unsigned short)(u >> 16);
}
__device__ inline float bf2f(unsigned short b) {
    return __uint_as_float(((unsigned)b) << 16);
}

__device__ inline void gload16(const void* g, void* l) {
    __builtin_amdgcn_global_load_lds(
        (const __attribute__((address_space(1))) void*)g,
        (__attribute__((address_space(3))) void*)l, 16, 0, 0);
}

// ---------------------------------------------------------------------------
// Split fp32 -> bf16 (hi) + bf16 (lo = bf16(x - hi)); 4 elems/thread
// ---------------------------------------------------------------------------
__global__ void k_split(const float* __restrict__ in, unsigned short* __restrict__ hi,
                        unsigned short* __restrict__ lo, int n4) {
    int t = blockIdx.x * 256 + threadIdx.x;
    if (t >= n4) return;
    float4 v = reinterpret_cast<const float4*>(in)[t];
    ushort4 h, l;
    h.x = f2bf(v.x); l.x = f2bf(v.x - bf2f(h.x));
    h.y = f2bf(v.y); l.y = f2bf(v.y - bf2f(h.y));
    h.z = f2bf(v.z); l.z = f2bf(v.z - bf2f(h.z));
    h.w = f2bf(v.w); l.w = f2bf(v.w - bf2f(h.w));
    reinterpret_cast<ushort4*>(hi)[t] = h;
    reinterpret_cast<ushort4*>(lo)[t] = l;
}

// hi-only split for the codebook (B's lo side dropped: dot ~= (hi+lo) . Hi)
__global__ void k_split_hi(const float* __restrict__ in, unsigned short* __restrict__ hi,
                           int n4) {
    int t = blockIdx.x * 256 + threadIdx.x;
    if (t >= n4) return;
    float4 v = reinterpret_cast<const float4*>(in)[t];
    ushort4 h;
    h.x = f2bf(v.x); h.y = f2bf(v.y); h.z = f2bf(v.z); h.w = f2bf(v.w);
    reinterpret_cast<ushort4*>(hi)[t] = h;
}

// ---------------------------------------------------------------------------
// c2[v] = sum(codebook[v]^2) fp32 (validated)
// ---------------------------------------------------------------------------
__global__ void k_c2(const float* __restrict__ cb, float* __restrict__ c2) {
    int row  = blockIdx.x * 4 + (threadIdx.x >> 6);
    int lane = threadIdx.x & 63;
    const float4* p = reinterpret_cast<const float4*>(cb + (size_t)row * DIM);
    float s = 0.f;
#pragma unroll
    for (int i = 0; i < 2; ++i) {
        float4 v = p[lane + i * 64];
        s += v.x * v.x + v.y * v.y + v.z * v.z + v.w * v.w;
    }
#pragma unroll
    for (int off = 32; off > 0; off >>= 1) s += __shfl_xor(s, off, 64);
    if (lane == 0) c2[row] = s;
}

// ---------------------------------------------------------------------------
// bf16 MFMA GEMM (virtual K = 1024: [xhi;xlo] x cbhi) + fused per-tile
// top-2 argmin epilogue. 128x128 tile, BK=64, 4 waves of 32 rows x 128 cols.
// LDS tiles [128 rows][64 bf16] with XOR swizzle (byte ^= (row&7)<<4) applied
// via pre-swizzled global source (linear global_load_lds dest) + swizzled read.
// This is the round-2 validated structure (775 TF, 0 bank conflicts).
// ---------------------------------------------------------------------------
__launch_bounds__(256, 2)
__global__ void k_mfma_argmin(const unsigned short* __restrict__ xhi,
                              const unsigned short* __restrict__ xlo,
                              const unsigned short* __restrict__ cbhi,
                              const float* __restrict__ c2,
                              float4* __restrict__ part) {
    __shared__ __align__(16) char As[128 * 128];   // 16 KB
    __shared__ __align__(16) char Bs[128 * 128];   // 16 KB
    const int tid  = threadIdx.x;
    const int w    = tid >> 6;
    const int lane = tid & 63;
    const int l15  = lane & 15;
    const int lg   = lane >> 4;
    const int rowBase = blockIdx.y * 128;
    const int colBase = blockIdx.x * 128;

    f32x4 acc[2][8];
#pragma unroll
    for (int mi = 0; mi < 2; ++mi)
#pragma unroll
        for (int nj = 0; nj < 8; ++nj) acc[mi][nj] = (f32x4)0.f;

    // staging constants: chunk = 1024B = 8 rows of 128B; lane covers
    // physical (r = 8*chunk + lane>>3, slot = lane&7); source slot ^= row&7
    const int r8     = lane >> 3;
    const int srcoff = ((lane & 7) ^ r8) << 4;

    for (int kt = 0; kt < 16; ++kt) {
        const int phase = kt >> 3;            // 0: hi*Hi  1: lo*Hi
        const int kb    = (kt & 7) << 7;      // byte offset within 1024B row
        const char* Asrc = (const char*)(phase ? xlo : xhi);
        if (kt) __syncthreads();
#pragma unroll
        for (int t = 0; t < 4; ++t) {
            int i  = 4 * w + t;               // chunk index 0..15
            int r0 = 8 * i;
            gload16(Asrc + (size_t)(rowBase + r0 + r8) * 1024 + kb + srcoff,
                    As + 1024 * i);
            gload16((const char*)cbhi + (size_t)(colBase + r0 + r8) * 1024 + kb + srcoff,
                    Bs + 1024 * i);
        }
        __syncthreads();
#pragma unroll
        for (int kk = 0; kk < 2; ++kk) {
            const int ob = kk * 64 + lg * 16;
            short8 a[2], b[8];
#pragma unroll
            for (int mi = 0; mi < 2; ++mi) {
                int r = w * 32 + mi * 16 + l15;
                a[mi] = *(const short8*)(As + r * 128 + (ob ^ ((r & 7) << 4)));
            }
#pragma unroll
            for (int nj = 0; nj < 8; ++nj) {
                int r = nj * 16 + l15;
                b[nj] = *(const short8*)(Bs + r * 128 + (ob ^ ((r & 7) << 4)));
            }
#pragma unroll
            for (int mi = 0; mi < 2; ++mi)
#pragma unroll
                for (int nj = 0; nj < 8; ++nj)
                    acc[mi][nj] = __builtin_amdgcn_mfma_f32_16x16x32_bf16(
                        a[mi], b[nj], acc[mi][nj], 0, 0, 0);
        }
    }

    // Epilogue: score = c2[v] - 2*dot; per-row top-2 over this block's 128 cols.
    // C layout (m89): col = lane&15, row = 4*(lane>>4) + reg.
    float c2v[8];
#pragma unroll
    for (int nj = 0; nj < 8; ++nj) c2v[nj] = c2[colBase + nj * 16 + l15];

#pragma unroll
    for (int mi = 0; mi < 2; ++mi) {
#pragma unroll
        for (int reg = 0; reg < 4; ++reg) {
            float s1 = INFINITY, s2 = INFINITY;
            int   i1 = 0x7fffffff, i2 = 0x7fffffff;
#pragma unroll
            for (int nj = 0; nj < 8; ++nj) {
                float s = fmaf(-2.f, acc[mi][nj][reg], c2v[nj]);
                int   v = colBase + nj * 16 + l15;
                if (s < s1 || (s == s1 && v < i1)) { s2 = s1; i2 = i1; s1 = s; i1 = v; }
                else if (s < s2 || (s == s2 && v < i2)) { s2 = s; i2 = v; }
            }
#pragma unroll
            for (int off = 1; off < 16; off <<= 1) {   // butterfly over 16 cols-lanes
                float t1 = __shfl_xor(s1, off, 64); int j1 = __shfl_xor(i1, off, 64);
                float t2 = __shfl_xor(s2, off, 64); int j2 = __shfl_xor(i2, off, 64);
                bool bfirst = (t1 < s1) || (t1 == s1 && j1 < i1);
                if (bfirst) {
                    float n2s; int n2i;
                    if (s1 < t2 || (s1 == t2 && i1 < j2)) { n2s = s1; n2i = i1; }
                    else                                   { n2s = t2; n2i = j2; }
                    s1 = t1; i1 = j1; s2 = n2s; i2 = n2i;
                } else {
                    if (t1 < s2 || (t1 == s2 && j1 < i2)) { s2 = t1; i2 = j1; }
                }
            }
            if (l15 == 0) {
                int row = rowBase + w * 32 + mi * 16 + 4 * lg + reg;
                part[(size_t)row * 64 + blockIdx.x] =
                    make_float4(s1, __int_as_float(i1), s2, __int_as_float(i2));
            }
        }
    }
}

// ---------------------------------------------------------------------------
// Per-row final: approx global min over 64 tile-top2s; exact fp32 rescore of
// every candidate within min+1.0 (>18 sigma of split error); lexicographic
// (score, idx) min == reference argmin semantics.
// ---------------------------------------------------------------------------
__global__ void k_select(const float4* __restrict__ part,
                         const float* __restrict__ x,
                         const float* __restrict__ cb,
                         const float* __restrict__ c2,
                         float* __restrict__ out_idx_f,
                         int* __restrict__ idx_i,
                         int* __restrict__ used) {
    int wv   = threadIdx.x >> 6;
    int lane = threadIdx.x & 63;
    int row  = blockIdx.x * 4 + wv;
    float4 p = part[(size_t)row * 64 + lane];
    float s1 = p.x; int i1 = __float_as_int(p.y);
    float s2 = p.z; int i2 = __float_as_int(p.w);
    float gm = s1;
#pragma unroll
    for (int off = 1; off < 64; off <<= 1) gm = fminf(gm, __shfl_xor(gm, off, 64));
    float thresh = gm + 1.0f;
    unsigned long long m1 = __ballot(s1 <= thresh);
    unsigned long long m2 = __ballot(s2 <= thresh);
    float be = INFINITY; int bi = 0x7fffffff;
    const float4* xr = reinterpret_cast<const float4*>(x + (size_t)row * DIM);
    while (m1 | m2) {
        int vi;
        if (m1) { int t = __ffsll(m1) - 1; m1 &= m1 - 1; vi = __shfl(i1, t); }
        else    { int t = __ffsll(m2) - 1; m2 &= m2 - 1; vi = __shfl(i2, t); }
        const float4* cr = reinterpret_cast<const float4*>(cb + (size_t)vi * DIM);
        float d = 0.f;
#pragma unroll
        for (int q = 0; q < 2; ++q) {
            float4 a = xr[q * 64 + lane];
            float4 b = cr[q * 64 + lane];
            d += a.x * b.x + a.y * b.y + a.z * b.z + a.w * b.w;
        }
#pragma unroll
        for (int off = 1; off < 64; off <<= 1) d += __shfl_xor(d, off, 64);
        float se = c2[vi] - 2.f * d;
        if (se < be || (se == be && vi < bi)) { be = se; bi = vi; }
    }
    if (lane == 0) {
        out_idx_f[row] = (float)bi;
        idx_i[row]     = bi;
        used[bi]       = 1;
    }
}

__global__ void k_streak(const int* __restrict__ streak_in,
                         const int* __restrict__ used,
                         float* __restrict__ out) {
    int v = blockIdx.x * 256 + threadIdx.x;
    if (v < VOCAB) out[v] = used[v] ? 0.f : (float)(streak_in[v] + 1);
}

__global__ void k_gather(const float* __restrict__ cb,
                         const int* __restrict__ idx_i,
                         float* __restrict__ out) {
    size_t t  = (size_t)blockIdx.x * 256 + threadIdx.x;
    int    n  = (int)(t >> 7);
    int    d4 = (int)(t & 127);
    reinterpret_cast<float4*>(out)[t] =
        reinterpret_cast<const float4*>(cb + (size_t)idx_i[n] * DIM)[d4];
}

extern "C" void kernel_launch(void* const* d_in, const int* in_sizes, int n_in,
                              void* d_out, int out_size, void* d_ws, size_t ws_size,
                              hipStream_t stream) {
    const float* x      = (const float*)d_in[0];
    const float* cb     = (const float*)d_in[1];
    const int*   streak = (const int*)d_in[2];

    float* out       = (float*)d_out;
    float* out_embed = out;
    float* out_idx   = out + (size_t)N_ROWS * DIM;
    float* out_strk  = out_idx + N_ROWS;

    char* ws = (char*)d_ws;
    unsigned short* xhi  = (unsigned short*)(ws);                 // 16 MB
    unsigned short* xlo  = (unsigned short*)(ws + (16u << 20));   // 16 MB
    unsigned short* cbhi = (unsigned short*)(ws + (32u << 20));   // 8 MB
    float* c2    = (float*)(ws + (48u << 20));                    // 32 KB
    int*   idx_i = (int*)(ws + (48u << 20) + (1u << 16));         // 64 KB
    int*   used  = (int*)(ws + (48u << 20) + (2u << 16));         // 32 KB
    float4* part = (float4*)(ws + (49u << 20));                   // 16 MB

    hipMemsetAsync(used, 0, VOCAB * sizeof(int), stream);
    k_split<<<(N_ROWS * DIM / 4) / 256, 256, 0, stream>>>(x, xhi, xlo, N_ROWS * DIM / 4);
    k_split_hi<<<(VOCAB * DIM / 4) / 256, 256, 0, stream>>>(cb, cbhi, VOCAB * DIM / 4);
    k_c2<<<VOCAB / 4, 256, 0, stream>>>(cb, c2);
    k_mfma_argmin<<<dim3(VOCAB / 128, N_ROWS / 128), 256, 0, stream>>>(
        xhi, xlo, cbhi, c2, part);
    k_select<<<N_ROWS / 4, 256, 0, stream>>>(part, x, cb, c2, out_idx, idx_i, used);
    k_streak<<<VOCAB / 256, 256, 0, stream>>>(streak, used, out_strk);
    k_gather<<<(N_ROWS * DIM / 4) / 256, 256, 0, stream>>>(cb, idx_i, out_embed);
}

// Round 5
// 350.663 us; speedup vs baseline: 3.8084x; 1.1507x over previous
//
#include <hip/hip_runtime.h>
#include <hip/hip_bf16.h>
#include <math.h>

// Problem: input (16,1024,512) f32, codebook (8192,512) f32
#define N_ROWS 16384
#define DIM    512
#define VOCAB  8192

typedef __attribute__((ext_vector_type(8))) short short8;
typedef __attribute__((ext_vector_type(4))) float f32x4;

__device__ inline unsigned short f2bf(float f) {      // RNE f32 -> bf16 bits
    unsigned u = __float_as_uint(f);
    u += 0x7fff + ((u >> 16) & 1);
    return (unsigned short)(u >> 16);
}

__device__ inline void gload16(const void* g, void* l) {
    __builtin_amdgcn_global_load_lds(
        (const __attribute__((address_space(1))) void*)g,
        (__attribute__((address_space(3))) void*)l, 16, 0, 0);
}

// ---------------------------------------------------------------------------
// fp32 -> bf16 (hi only; exact fp32 rescore makes lo unnecessary at K=512)
// ---------------------------------------------------------------------------
__global__ void k_split_hi(const float* __restrict__ in, unsigned short* __restrict__ hi,
                           int n4) {
    int t = blockIdx.x * 256 + threadIdx.x;
    if (t >= n4) return;
    float4 v = reinterpret_cast<const float4*>(in)[t];
    ushort4 h;
    h.x = f2bf(v.x); h.y = f2bf(v.y); h.z = f2bf(v.z); h.w = f2bf(v.w);
    reinterpret_cast<ushort4*>(hi)[t] = h;
}

// ---------------------------------------------------------------------------
// c2[v] = sum(codebook[v]^2) fp32 (validated)
// ---------------------------------------------------------------------------
__global__ void k_c2(const float* __restrict__ cb, float* __restrict__ c2) {
    int row  = blockIdx.x * 4 + (threadIdx.x >> 6);
    int lane = threadIdx.x & 63;
    const float4* p = reinterpret_cast<const float4*>(cb + (size_t)row * DIM);
    float s = 0.f;
#pragma unroll
    for (int i = 0; i < 2; ++i) {
        float4 v = p[lane + i * 64];
        s += v.x * v.x + v.y * v.y + v.z * v.z + v.w * v.w;
    }
#pragma unroll
    for (int off = 32; off > 0; off >>= 1) s += __shfl_xor(s, off, 64);
    if (lane == 0) c2[row] = s;
}

// ---------------------------------------------------------------------------
// bf16 MFMA GEMM (K = 512: bf16(x) x bf16(cb)) + fused per-tile top-2 argmin.
// 128x128 tile, BK=64, 4 waves of 32 rows x 128 cols (round-2-validated
// fragment/swizzle layout, 0 bank conflicts) + minimal 2-phase LDS double
// buffer: issue next tile's global_load_lds BEFORE computing current tile,
// one vmcnt(0) + raw s_barrier per tile (no full __syncthreads drain).
// ---------------------------------------------------------------------------
__launch_bounds__(256, 2)
__global__ void k_mfma_argmin(const unsigned short* __restrict__ xhi,
                              const unsigned short* __restrict__ cbhi,
                              const float* __restrict__ c2,
                              float4* __restrict__ part) {
    __shared__ __align__(16) char As[2 * 16384];   // [buf][128 rows][64 bf16]
    __shared__ __align__(16) char Bs[2 * 16384];
    const int tid  = threadIdx.x;
    const int w    = tid >> 6;
    const int lane = tid & 63;
    const int l15  = lane & 15;
    const int lg   = lane >> 4;
    const int rowBase = blockIdx.y * 128;
    const int colBase = blockIdx.x * 128;

    f32x4 acc[2][8];
#pragma unroll
    for (int mi = 0; mi < 2; ++mi)
#pragma unroll
        for (int nj = 0; nj < 8; ++nj) acc[mi][nj] = (f32x4)0.f;

    // staging: chunk = 1024B = 8 rows of 128B; lane covers
    // (r = 8*chunk + lane>>3, slot = lane&7); source slot ^= row&7 so that a
    // swizzled ds_read (slot ^ row&7) recovers linear data (rule 21).
    const int r8     = lane >> 3;
    const int srcoff = ((lane & 7) ^ r8) << 4;

#define STAGE(BUF, KT) do {                                                   \
    const int _kb = (KT) << 7;                                                \
    _Pragma("unroll") for (int _t = 0; _t < 4; ++_t) {                        \
        int _i = 4 * w + _t;                                                  \
        int _r0 = 8 * _i;                                                     \
        gload16((const char*)xhi + (size_t)(rowBase + _r0 + r8) * 1024 +      \
                    _kb + srcoff, As + (BUF) * 16384 + 1024 * _i);            \
        gload16((const char*)cbhi + (size_t)(colBase + _r0 + r8) * 1024 +     \
                    _kb + srcoff, Bs + (BUF) * 16384 + 1024 * _i);            \
    } } while (0)

    STAGE(0, 0);
    asm volatile("s_waitcnt vmcnt(0)" ::: "memory");
    asm volatile("s_barrier" ::: "memory");

    for (int kt = 0; kt < 8; ++kt) {               // 8 K-tiles of 64 = K 512
        const int cur = kt & 1;
        if (kt < 7) STAGE(cur ^ 1, kt + 1);        // prefetch next tile
        __builtin_amdgcn_sched_barrier(0);         // loads issue before compute
        const char* Ab = As + cur * 16384;
        const char* Bb = Bs + cur * 16384;
#pragma unroll
        for (int kk = 0; kk < 2; ++kk) {
            const int ob = kk * 64 + lg * 16;
            short8 a[2], b[8];
#pragma unroll
            for (int mi = 0; mi < 2; ++mi) {
                int r = w * 32 + mi * 16 + l15;
                a[mi] = *(const short8*)(Ab + r * 128 + (ob ^ ((r & 7) << 4)));
            }
#pragma unroll
            for (int nj = 0; nj < 8; ++nj) {
                int r = nj * 16 + l15;
                b[nj] = *(const short8*)(Bb + r * 128 + (ob ^ ((r & 7) << 4)));
            }
#pragma unroll
            for (int mi = 0; mi < 2; ++mi)
#pragma unroll
                for (int nj = 0; nj < 8; ++nj)
                    acc[mi][nj] = __builtin_amdgcn_mfma_f32_16x16x32_bf16(
                        a[mi], b[nj], acc[mi][nj], 0, 0, 0);
        }
        asm volatile("s_waitcnt vmcnt(0)" ::: "memory");  // prefetch landed
        asm volatile("s_barrier" ::: "memory");           // all waves done
    }

    // Epilogue: score = c2[v] - 2*dot; per-row top-2 over this block's 128 cols.
    // C layout (m89): col = lane&15, row = 4*(lane>>4) + reg.
    float c2v[8];
#pragma unroll
    for (int nj = 0; nj < 8; ++nj) c2v[nj] = c2[colBase + nj * 16 + l15];

#pragma unroll
    for (int mi = 0; mi < 2; ++mi) {
#pragma unroll
        for (int reg = 0; reg < 4; ++reg) {
            float s1 = INFINITY, s2 = INFINITY;
            int   i1 = 0x7fffffff, i2 = 0x7fffffff;
#pragma unroll
            for (int nj = 0; nj < 8; ++nj) {
                float s = fmaf(-2.f, acc[mi][nj][reg], c2v[nj]);
                int   v = colBase + nj * 16 + l15;
                if (s < s1 || (s == s1 && v < i1)) { s2 = s1; i2 = i1; s1 = s; i1 = v; }
                else if (s < s2 || (s == s2 && v < i2)) { s2 = s; i2 = v; }
            }
#pragma unroll
            for (int off = 1; off < 16; off <<= 1) {   // butterfly over 16 col-lanes
                float t1 = __shfl_xor(s1, off, 64); int j1 = __shfl_xor(i1, off, 64);
                float t2 = __shfl_xor(s2, off, 64); int j2 = __shfl_xor(i2, off, 64);
                bool bfirst = (t1 < s1) || (t1 == s1 && j1 < i1);
                if (bfirst) {
                    float n2s; int n2i;
                    if (s1 < t2 || (s1 == t2 && i1 < j2)) { n2s = s1; n2i = i1; }
                    else                                   { n2s = t2; n2i = j2; }
                    s1 = t1; i1 = j1; s2 = n2s; i2 = n2i;
                } else {
                    if (t1 < s2 || (t1 == s2 && j1 < i2)) { s2 = t1; i2 = j1; }
                }
            }
            if (l15 == 0) {
                int row = rowBase + w * 32 + mi * 16 + 4 * lg + reg;
                part[(size_t)row * 64 + blockIdx.x] =
                    make_float4(s1, __int_as_float(i1), s2, __int_as_float(i2));
            }
        }
    }
}

// ---------------------------------------------------------------------------
// Per-row final: approx global min over 64 tile-top2s; exact fp32 rescore of
// every candidate within min+1.0 (>14 sigma of bf16 approx error);
// lexicographic (score, idx) min == reference argmin semantics.
// ---------------------------------------------------------------------------
__global__ void k_select(const float4* __restrict__ part,
                         const float* __restrict__ x,
                         const float* __restrict__ cb,
                         const float* __restrict__ c2,
                         float* __restrict__ out_idx_f,
                         int* __restrict__ idx_i,
                         int* __restrict__ used) {
    int wv   = threadIdx.x >> 6;
    int lane = threadIdx.x & 63;
    int row  = blockIdx.x * 4 + wv;
    float4 p = part[(size_t)row * 64 + lane];
    float s1 = p.x; int i1 = __float_as_int(p.y);
    float s2 = p.z; int i2 = __float_as_int(p.w);
    float gm = s1;
#pragma unroll
    for (int off = 1; off < 64; off <<= 1) gm = fminf(gm, __shfl_xor(gm, off, 64));
    float thresh = gm + 1.0f;
    unsigned long long m1 = __ballot(s1 <= thresh);
    unsigned long long m2 = __ballot(s2 <= thresh);
    float be = INFINITY; int bi = 0x7fffffff;
    const float4* xr = reinterpret_cast<const float4*>(x + (size_t)row * DIM);
    while (m1 | m2) {
        int vi;
        if (m1) { int t = __ffsll(m1) - 1; m1 &= m1 - 1; vi = __shfl(i1, t); }
        else    { int t = __ffsll(m2) - 1; m2 &= m2 - 1; vi = __shfl(i2, t); }
        const float4* cr = reinterpret_cast<const float4*>(cb + (size_t)vi * DIM);
        float d = 0.f;
#pragma unroll
        for (int q = 0; q < 2; ++q) {
            float4 a = xr[q * 64 + lane];
            float4 b = cr[q * 64 + lane];
            d += a.x * b.x + a.y * b.y + a.z * b.z + a.w * b.w;
        }
#pragma unroll
        for (int off = 1; off < 64; off <<= 1) d += __shfl_xor(d, off, 64);
        float se = c2[vi] - 2.f * d;
        if (se < be || (se == be && vi < bi)) { be = se; bi = vi; }
    }
    if (lane == 0) {
        out_idx_f[row] = (float)bi;
        idx_i[row]     = bi;
        used[bi]       = 1;
    }
}

__global__ void k_streak(const int* __restrict__ streak_in,
                         const int* __restrict__ used,
                         float* __restrict__ out) {
    int v = blockIdx.x * 256 + threadIdx.x;
    if (v < VOCAB) out[v] = used[v] ? 0.f : (float)(streak_in[v] + 1);
}

__global__ void k_gather(const float* __restrict__ cb,
                         const int* __restrict__ idx_i,
                         float* __restrict__ out) {
    size_t t  = (size_t)blockIdx.x * 256 + threadIdx.x;
    int    n  = (int)(t >> 7);
    int    d4 = (int)(t & 127);
    reinterpret_cast<float4*>(out)[t] =
        reinterpret_cast<const float4*>(cb + (size_t)idx_i[n] * DIM)[d4];
}

extern "C" void kernel_launch(void* const* d_in, const int* in_sizes, int n_in,
                              void* d_out, int out_size, void* d_ws, size_t ws_size,
                              hipStream_t stream) {
    const float* x      = (const float*)d_in[0];
    const float* cb     = (const float*)d_in[1];
    const int*   streak = (const int*)d_in[2];

    float* out       = (float*)d_out;
    float* out_embed = out;
    float* out_idx   = out + (size_t)N_ROWS * DIM;
    float* out_strk  = out_idx + N_ROWS;

    char* ws = (char*)d_ws;
    unsigned short* xhi  = (unsigned short*)(ws);                 // 16 MB
    unsigned short* cbhi = (unsigned short*)(ws + (32u << 20));   // 8 MB
    float* c2    = (float*)(ws + (48u << 20));                    // 32 KB
    int*   idx_i = (int*)(ws + (48u << 20) + (1u << 16));         // 64 KB
    int*   used  = (int*)(ws + (48u << 20) + (2u << 16));         // 32 KB
    float4* part = (float4*)(ws + (49u << 20));                   // 16 MB

    hipMemsetAsync(used, 0, VOCAB * sizeof(int), stream);
    k_split_hi<<<(N_ROWS * DIM / 4) / 256, 256, 0, stream>>>(x, xhi, N_ROWS * DIM / 4);
    k_split_hi<<<(VOCAB * DIM / 4) / 256, 256, 0, stream>>>(cb, cbhi, VOCAB * DIM / 4);
    k_c2<<<VOCAB / 4, 256, 0, stream>>>(cb, c2);
    k_mfma_argmin<<<dim3(VOCAB / 128, N_ROWS / 128), 256, 0, stream>>>(
        xhi, cbhi, c2, part);
    k_select<<<N_ROWS / 4, 256, 0, stream>>>(part, x, cb, c2, out_idx, idx_i, used);
    k_streak<<<VOCAB / 256, 256, 0, stream>>>(streak, used, out_strk);
    k_gather<<<(N_ROWS * DIM / 4) / 256, 256, 0, stream>>>(cb, idx_i, out_embed);
}